// Round 1
// baseline (396.407 us; speedup 1.0000x reference)
//
#include <hip/hip_runtime.h>
#include <hip/hip_bf16.h>

// SlotAttention fused implementation.
// Pipeline: wt_transpose -> init(slots,q1) -> phaseA(LN+GEMM k,v + attn iter1 partials)
//           -> update(reduce+GRU+MLP -> slots1,q2) -> iter2(attn -> d_out, partials)
//           -> update(final slots -> d_out)

#define N_TOK 262144
#define CIN 512
#define TILE_M 64
#define NBLK_A 512
#define NBLK_I2 1024

typedef __attribute__((ext_vector_type(8))) short short8;
typedef __attribute__((ext_vector_type(4))) float f32x4;

__device__ __forceinline__ unsigned short f2bf(float f) {
    union { float f; unsigned u; } v; v.f = f;
    unsigned r = v.u + 0x7FFFu + ((v.u >> 16) & 1u);
    return (unsigned short)(r >> 16);
}
__device__ __forceinline__ float bf2f(unsigned short u) {
    union { unsigned u; float f; } v; v.u = ((unsigned)u) << 16;
    return v.f;
}
__device__ __forceinline__ float sigmoidf_(float x) { return 1.f / (1.f + expf(-x)); }

// q = LN(slot)*g+b @ W * scale, computed per-wave (64 lanes hold the 64-dim slot).
__device__ __forceinline__ float q_from_slot(float v, const float* __restrict__ g,
                                             const float* __restrict__ b,
                                             const float* __restrict__ W, int lane) {
    float s = v, s2 = v * v;
#pragma unroll
    for (int d = 1; d < 64; d <<= 1) { s += __shfl_xor(s, d); s2 += __shfl_xor(s2, d); }
    float mean = s * (1.f / 64.f);
    float var = s2 * (1.f / 64.f) - mean * mean;
    float rstd = rsqrtf(var + 1e-3f);
    float hl = (v - mean) * rstd * g[lane] + b[lane];
    float acc = 0.f;
    for (int i = 0; i < 64; ++i) acc += __shfl(hl, i) * W[i * 64 + lane];
    return acc * 0.125f;  // scale = D^-0.5
}

// ---------------- Wt transpose: Wt[c][i] = (c<64?Wk:Wv)[i][c-], bf16 ----------------
__global__ __launch_bounds__(256) void wt_kernel(const float* __restrict__ Wk,
                                                 const float* __restrict__ Wv,
                                                 unsigned short* __restrict__ Wt) {
    for (int e = 0; e < 4; ++e) {
        int idx = blockIdx.x * 1024 + e * 256 + threadIdx.x;
        int c = idx >> 9, i = idx & 511;
        float v = (c < 64) ? Wk[i * 64 + c] : Wv[i * 64 + (c - 64)];
        Wt[idx] = f2bf(v);
    }
}

// ---------------- init: slots0 + q1 ----------------
__global__ __launch_bounds__(256) void init_kernel(
    const float* __restrict__ noise_fg, const float* __restrict__ noise_bg,
    const float* __restrict__ mu_fg, const float* __restrict__ ls_fg,
    const float* __restrict__ mu_bg, const float* __restrict__ ls_bg,
    const float* __restrict__ qbg_g, const float* __restrict__ qbg_b, const float* __restrict__ qbg_W,
    const float* __restrict__ qfg_g, const float* __restrict__ qfg_b, const float* __restrict__ qfg_W,
    float* __restrict__ slots_ws, float* __restrict__ q_ws) {
    int t = threadIdx.x;
    if (t < 192) {
        int s = t >> 6, c = t & 63;
        float v = (s == 0) ? (mu_bg[c] + expf(ls_bg[c]) * noise_bg[c])
                           : (mu_fg[c] + expf(ls_fg[c]) * noise_fg[(s - 1) * 64 + c]);
        slots_ws[t] = v;
        const float* g = s ? qfg_g : qbg_g;
        const float* b = s ? qfg_b : qbg_b;
        const float* W = s ? qfg_W : qbg_W;
        q_ws[t] = q_from_slot(v, g, b, W, c);
    }
}

// ---------------- phase A: LN + k,v GEMM + iter1 attention partials ----------------
__global__ __launch_bounds__(256, 2) void phaseA_kernel(
    const float* __restrict__ x, const float* __restrict__ ln_g, const float* __restrict__ ln_b,
    const unsigned short* __restrict__ Wt, const float* __restrict__ qv,
    unsigned short* __restrict__ kb, unsigned short* __restrict__ vb,
    float* __restrict__ partials) {
    __shared__ unsigned short SA[TILE_M * CIN];  // 64KB: xln bf16 (swizzled) / aliased as kv f32
    __shared__ float q_s[192];
    __shared__ float w_s[64 * 4];
    float* kvf = (float*)SA;  // [64][130] f32 after MFMA

    const int t = threadIdx.x;
    const int lane = t & 63;
    const int w = t >> 6;

    if (t < 192) q_s[t] = qv[t];

    // hoisted LN gamma/beta for this lane's columns
    const float4 ga = ((const float4*)ln_g)[lane];
    const float4 gb = ((const float4*)ln_g)[64 + lane];
    const float4 ba = ((const float4*)ln_b)[lane];
    const float4 bb = ((const float4*)ln_b)[64 + lane];

    // hoisted B fragments: wave w owns output cols [w*32, w*32+32)
    short8 bfrag[16][2];
#pragma unroll
    for (int kk = 0; kk < 16; ++kk)
#pragma unroll
        for (int nt = 0; nt < 2; ++nt) {
            int row = w * 32 + nt * 16 + (lane & 15);
            int off = kk * 32 + ((lane >> 4) << 3);
            bfrag[kk][nt] = *(const short8*)(Wt + (size_t)row * 512 + off);
        }

    float upd_acc = 0.f;  // t<192: (s,c) partial
    float sw_acc = 0.f;   // t in [192,195): sum_w partial

    for (int tile = blockIdx.x; tile < N_TOK / TILE_M; tile += NBLK_A) {
        const size_t row0 = (size_t)tile * TILE_M;
        __syncthreads();  // protect SA from previous iteration readers

        // ---- P1: LN + stage xln (bf16, XOR-swizzled) ----
        for (int rr = 0; rr < 16; ++rr) {
            int r = w * 16 + rr;
            const float4* xr = (const float4*)(x + (row0 + r) * CIN);
            float4 a = xr[lane];
            float4 b = xr[64 + lane];
            float s = (a.x + a.y) + (a.z + a.w) + (b.x + b.y) + (b.z + b.w);
            float s2 = (a.x * a.x + a.y * a.y) + (a.z * a.z + a.w * a.w) +
                       (b.x * b.x + b.y * b.y) + (b.z * b.z + b.w * b.w);
#pragma unroll
            for (int d = 1; d < 64; d <<= 1) { s += __shfl_xor(s, d); s2 += __shfl_xor(s2, d); }
            float mean = s * (1.f / 512.f);
            float var = s2 * (1.f / 512.f) - mean * mean;
            float rstd = rsqrtf(var + 1e-3f);
            float va0 = (a.x - mean) * rstd * ga.x + ba.x;
            float va1 = (a.y - mean) * rstd * ga.y + ba.y;
            float va2 = (a.z - mean) * rstd * ga.z + ba.z;
            float va3 = (a.w - mean) * rstd * ga.w + ba.w;
            float vb0 = (b.x - mean) * rstd * gb.x + bb.x;
            float vb1 = (b.y - mean) * rstd * gb.y + bb.y;
            float vb2 = (b.z - mean) * rstd * gb.z + bb.z;
            float vb3 = (b.w - mean) * rstd * gb.w + bb.w;
            uint2 pa, pb;
            pa.x = (unsigned)f2bf(va0) | ((unsigned)f2bf(va1) << 16);
            pa.y = (unsigned)f2bf(va2) | ((unsigned)f2bf(va3) << 16);
            pb.x = (unsigned)f2bf(vb0) | ((unsigned)f2bf(vb1) << 16);
            pb.y = (unsigned)f2bf(vb2) | ((unsigned)f2bf(vb3) << 16);
            char* rowbase = (char*)SA + r * 1024;
            *(uint2*)(rowbase + ((8 * lane) ^ ((r & 7) << 4))) = pa;
            *(uint2*)(rowbase + ((512 + 8 * lane) ^ ((r & 7) << 4))) = pb;
        }
        __syncthreads();

        // ---- P2: MFMA ----
        f32x4 acc[4][2];
#pragma unroll
        for (int m = 0; m < 4; ++m) {
            acc[m][0] = (f32x4){0.f, 0.f, 0.f, 0.f};
            acc[m][1] = (f32x4){0.f, 0.f, 0.f, 0.f};
        }
#pragma unroll
        for (int kk = 0; kk < 16; ++kk) {
#pragma unroll
            for (int m = 0; m < 4; ++m) {
                int row = m * 16 + (lane & 15);
                int boff = (kk * 64 + ((lane >> 4) << 4)) ^ ((row & 7) << 4);
                short8 af = *(const short8*)((const char*)SA + row * 1024 + boff);
                acc[m][0] = __builtin_amdgcn_mfma_f32_16x16x32_bf16(af, bfrag[kk][0], acc[m][0], 0, 0, 0);
                acc[m][1] = __builtin_amdgcn_mfma_f32_16x16x32_bf16(af, bfrag[kk][1], acc[m][1], 0, 0, 0);
            }
        }
        __syncthreads();  // all SA reads done before aliasing as kvf

        // ---- P3: acc -> kvf [64][130] ----
#pragma unroll
        for (int m = 0; m < 4; ++m)
#pragma unroll
            for (int n = 0; n < 2; ++n)
#pragma unroll
                for (int j = 0; j < 4; ++j) {
                    int row = m * 16 + ((lane >> 4) * 4 + j);
                    int col = w * 32 + n * 16 + (lane & 15);
                    kvf[row * 130 + col] = acc[m][n][j];
                }
        __syncthreads();

        // ---- P4: bf16 store of k,v + wave0 computes softmax weights ----
        {
            int r = t >> 2, q4 = t & 3;
            unsigned short* dst = ((q4 < 2) ? kb : vb) + (row0 + r) * 64 + (q4 & 1) * 32;
            const float* src = &kvf[r * 130 + q4 * 32];
#pragma unroll
            for (int j = 0; j < 32; j += 8) {
                float2 p0 = *(const float2*)(src + j);
                float2 p1 = *(const float2*)(src + j + 2);
                float2 p2 = *(const float2*)(src + j + 4);
                float2 p3 = *(const float2*)(src + j + 6);
                uint4 o;
                o.x = (unsigned)f2bf(p0.x) | ((unsigned)f2bf(p0.y) << 16);
                o.y = (unsigned)f2bf(p1.x) | ((unsigned)f2bf(p1.y) << 16);
                o.z = (unsigned)f2bf(p2.x) | ((unsigned)f2bf(p2.y) << 16);
                o.w = (unsigned)f2bf(p3.x) | ((unsigned)f2bf(p3.y) << 16);
                *(uint4*)(dst + j) = o;
            }
        }
        if (t < 64) {
            int r = t;
            float l0 = 0.f, l1 = 0.f, l2 = 0.f;
#pragma unroll 8
            for (int c = 0; c < 64; c += 2) {
                float2 kv2 = *(const float2*)&kvf[r * 130 + c];
                l0 += kv2.x * q_s[c] + kv2.y * q_s[c + 1];
                l1 += kv2.x * q_s[64 + c] + kv2.y * q_s[64 + c + 1];
                l2 += kv2.x * q_s[128 + c] + kv2.y * q_s[128 + c + 1];
            }
            float mx = fmaxf(l0, fmaxf(l1, l2));
            float e0 = expf(l0 - mx), e1 = expf(l1 - mx), e2 = expf(l2 - mx);
            float inv = 1.f / (e0 + e1 + e2);
            w_s[r * 4 + 0] = e0 * inv + 1e-8f;
            w_s[r * 4 + 1] = e1 * inv + 1e-8f;
            w_s[r * 4 + 2] = e2 * inv + 1e-8f;
        }
        __syncthreads();

        // ---- P5: outer-product partial accumulate ----
        if (t < 192) {
            int s = t >> 6, c = t & 63;
            float a = 0.f;
            for (int r = 0; r < 64; ++r) a += w_s[r * 4 + s] * kvf[r * 130 + 64 + c];
            upd_acc += a;
        } else if (t < 195) {
            int s = t - 192;
            float a = 0.f;
            for (int r = 0; r < 64; ++r) a += w_s[r * 4 + s];
            sw_acc += a;
        }
    }
    if (t < 192) partials[(size_t)blockIdx.x * 256 + t] = upd_acc;
    else if (t < 195) partials[(size_t)blockIdx.x * 256 + t] = sw_acc;
}

// ---------------- iter 2: attention with q2, writes attn.T + partials ----------------
__global__ __launch_bounds__(256) void iter2_kernel(
    const unsigned short* __restrict__ kb, const unsigned short* __restrict__ vb,
    const float* __restrict__ qv, float* __restrict__ attn_out, float* __restrict__ partials) {
    __shared__ float q_s[192];
    __shared__ float w_s[256 * 4];
    __shared__ unsigned short v_lds[256 * 64];
    int t = threadIdx.x;
    if (t < 192) q_s[t] = qv[t];
    __syncthreads();
    size_t r = (size_t)blockIdx.x * 256 + t;
    const unsigned short* krow = kb + r * 64;
    float l0 = 0.f, l1 = 0.f, l2 = 0.f;
#pragma unroll
    for (int i = 0; i < 8; ++i) {
        uint4 u = *(const uint4*)(krow + i * 8);
        unsigned uu[4] = {u.x, u.y, u.z, u.w};
#pragma unroll
        for (int p = 0; p < 4; ++p) {
            float fa = bf2f((unsigned short)(uu[p] & 0xffffu));
            float fb = bf2f((unsigned short)(uu[p] >> 16));
            int c = i * 8 + p * 2;
            l0 += fa * q_s[c] + fb * q_s[c + 1];
            l1 += fa * q_s[64 + c] + fb * q_s[64 + c + 1];
            l2 += fa * q_s[128 + c] + fb * q_s[128 + c + 1];
        }
    }
    float mx = fmaxf(l0, fmaxf(l1, l2));
    float e0 = expf(l0 - mx), e1 = expf(l1 - mx), e2 = expf(l2 - mx);
    float inv = 1.f / (e0 + e1 + e2);
    float a0 = e0 * inv, a1 = e1 * inv, a2 = e2 * inv;
    attn_out[r] = a0;
    attn_out[(size_t)N_TOK + r] = a1;
    attn_out[2 * (size_t)N_TOK + r] = a2;
    w_s[t * 4 + 0] = a0 + 1e-8f;
    w_s[t * 4 + 1] = a1 + 1e-8f;
    w_s[t * 4 + 2] = a2 + 1e-8f;
    {
        const uint4* vr = (const uint4*)(vb + r * 64);
        uint4* vl = (uint4*)(v_lds + t * 64);
#pragma unroll
        for (int i = 0; i < 8; ++i) vl[i] = vr[i];
    }
    __syncthreads();
    if (t < 192) {
        int s = t >> 6, c = t & 63;
        float part = 0.f;
        for (int r2 = 0; r2 < 256; ++r2) part += w_s[r2 * 4 + s] * bf2f(v_lds[r2 * 64 + c]);
        partials[(size_t)blockIdx.x * 256 + t] = part;
    } else if (t < 195) {
        int s = t - 192;
        float part = 0.f;
        for (int r2 = 0; r2 < 256; ++r2) part += w_s[r2 * 4 + s];
        partials[(size_t)blockIdx.x * 256 + t] = part;
    }
}

// ---------------- update: reduce partials -> GRU -> MLP -> (q | out slots) ----------------
__global__ __launch_bounds__(256) void update_kernel(
    const float* __restrict__ partials, int nblk,
    float* __restrict__ slots_ws, float* __restrict__ q_ws,
    const float* __restrict__ gbg_k, const float* __restrict__ gbg_rk, const float* __restrict__ gbg_bias,
    const float* __restrict__ gfg_k, const float* __restrict__ gfg_rk, const float* __restrict__ gfg_bias,
    const float* __restrict__ mbg_g, const float* __restrict__ mbg_b, const float* __restrict__ mbg_W1,
    const float* __restrict__ mbg_b1, const float* __restrict__ mbg_W2, const float* __restrict__ mbg_b2,
    const float* __restrict__ mfg_g, const float* __restrict__ mfg_b, const float* __restrict__ mfg_W1,
    const float* __restrict__ mfg_b1, const float* __restrict__ mfg_W2, const float* __restrict__ mfg_b2,
    const float* __restrict__ qbg_g, const float* __restrict__ qbg_b, const float* __restrict__ qbg_W,
    const float* __restrict__ qfg_g, const float* __restrict__ qfg_b, const float* __restrict__ qfg_W,
    int compute_q, float* __restrict__ out_slots) {
    __shared__ float upd[192], hslots[192], swv[3];
    __shared__ float xm[192], hm[192], gout[64], lnv[64], hid[64];
    int t = threadIdx.x;
    if (t < 192) hslots[t] = slots_ws[t];
    if (t < 195) {
        float a0 = 0, a1 = 0, a2 = 0, a3 = 0;
        for (int b = 0; b < nblk; b += 4) {
            a0 += partials[(size_t)b * 256 + t];
            a1 += partials[(size_t)(b + 1) * 256 + t];
            a2 += partials[(size_t)(b + 2) * 256 + t];
            a3 += partials[(size_t)(b + 3) * 256 + t];
        }
        float tot = (a0 + a1) + (a2 + a3);
        if (t < 192) upd[t] = tot; else swv[t - 192] = tot;
    }
    __syncthreads();
    if (t < 192) upd[t] = upd[t] / swv[t >> 6];
    __syncthreads();

    for (int s = 0; s < 3; ++s) {
        const float* K = s ? gfg_k : gbg_k;
        const float* RK = s ? gfg_rk : gbg_rk;
        const float* BS = s ? gfg_bias : gbg_bias;
        if (t < 192) {
            float ax = BS[t], ah = BS[192 + t];
            const float* us = upd + s * 64;
            const float* hs = hslots + s * 64;
            for (int i = 0; i < 64; ++i) {
                ax += us[i] * K[i * 192 + t];
                ah += hs[i] * RK[i * 192 + t];
            }
            xm[t] = ax; hm[t] = ah;
        }
        __syncthreads();
        if (t < 64) {
            float z = sigmoidf_(xm[t] + hm[t]);
            float rg = sigmoidf_(xm[64 + t] + hm[64 + t]);
            float cand = tanhf(xm[128 + t] + rg * hm[128 + t]);
            gout[t] = z * hslots[s * 64 + t] + (1.f - z) * cand;
        }
        __syncthreads();
        const float* MG = s ? mfg_g : mbg_g;
        const float* MB = s ? mfg_b : mbg_b;
        const float* MW1 = s ? mfg_W1 : mbg_W1;
        const float* MB1 = s ? mfg_b1 : mbg_b1;
        const float* MW2 = s ? mfg_W2 : mbg_W2;
        const float* MB2 = s ? mfg_b2 : mbg_b2;
        if (t < 64) {
            float v = gout[t];
            float su = v, sq = v * v;
#pragma unroll
            for (int d = 1; d < 64; d <<= 1) { su += __shfl_xor(su, d); sq += __shfl_xor(sq, d); }
            float mean = su * (1.f / 64.f), var = sq * (1.f / 64.f) - mean * mean;
            float rstd = rsqrtf(var + 1e-3f);
            lnv[t] = (v - mean) * rstd * MG[t] + MB[t];
        }
        __syncthreads();
        if (t < 64) {
            float a = MB1[t];
            for (int i = 0; i < 64; ++i) a += lnv[i] * MW1[i * 64 + t];
            hid[t] = fmaxf(a, 0.f);
        }
        __syncthreads();
        if (t < 64) {
            float a = MB2[t];
            for (int i = 0; i < 64; ++i) a += hid[i] * MW2[i * 64 + t];
            hslots[s * 64 + t] = gout[t] + a;
        }
        __syncthreads();
    }
    if (t < 192) {
        slots_ws[t] = hslots[t];
        if (out_slots) out_slots[t] = hslots[t];
        if (compute_q) {
            int s = t >> 6, lane = t & 63;
            const float* g = s ? qfg_g : qbg_g;
            const float* b = s ? qfg_b : qbg_b;
            const float* W = s ? qfg_W : qbg_W;
            q_ws[t] = q_from_slot(hslots[t], g, b, W, lane);
        }
    }
}

extern "C" void kernel_launch(void* const* d_in, const int* in_sizes, int n_in,
                              void* d_out, int out_size, void* d_ws, size_t ws_size,
                              hipStream_t stream) {
    const float* x        = (const float*)d_in[0];
    const float* noise_fg = (const float*)d_in[1];
    const float* noise_bg = (const float*)d_in[2];
    const float* ln_g     = (const float*)d_in[3];
    const float* ln_b     = (const float*)d_in[4];
    const float* mu_fg    = (const float*)d_in[5];
    const float* ls_fg    = (const float*)d_in[6];
    const float* mu_bg    = (const float*)d_in[7];
    const float* ls_bg    = (const float*)d_in[8];
    const float* Wk       = (const float*)d_in[9];
    const float* Wv       = (const float*)d_in[10];
    const float* qfg_g    = (const float*)d_in[11];
    const float* qfg_b    = (const float*)d_in[12];
    const float* qfg_W    = (const float*)d_in[13];
    const float* qbg_g    = (const float*)d_in[14];
    const float* qbg_b    = (const float*)d_in[15];
    const float* qbg_W    = (const float*)d_in[16];
    const float* gfg_k    = (const float*)d_in[17];
    const float* gfg_rk   = (const float*)d_in[18];
    const float* gfg_bias = (const float*)d_in[19];
    const float* gbg_k    = (const float*)d_in[20];
    const float* gbg_rk   = (const float*)d_in[21];
    const float* gbg_bias = (const float*)d_in[22];
    const float* mfg_g    = (const float*)d_in[23];
    const float* mfg_b    = (const float*)d_in[24];
    const float* mfg_W1   = (const float*)d_in[25];
    const float* mfg_b1   = (const float*)d_in[26];
    const float* mfg_W2   = (const float*)d_in[27];
    const float* mfg_b2   = (const float*)d_in[28];
    const float* mbg_g    = (const float*)d_in[29];
    const float* mbg_b    = (const float*)d_in[30];
    const float* mbg_W1   = (const float*)d_in[31];
    const float* mbg_b1   = (const float*)d_in[32];
    const float* mbg_W2   = (const float*)d_in[33];
    const float* mbg_b2   = (const float*)d_in[34];

    char* ws = (char*)d_ws;
    unsigned short* Wt = (unsigned short*)ws;                 // 128*512*2   = 131072 B
    unsigned short* kb = (unsigned short*)(ws + 131072);      // N*64*2      = 32 MB
    unsigned short* vb = kb + (size_t)N_TOK * 64;             // 32 MB
    float* slots_ws = (float*)(ws + 131072 + (size_t)2 * N_TOK * 64 * 2);
    float* q_ws = slots_ws + 192;
    float* partials = q_ws + 192;                             // up to 1024*256 f32 = 1 MB

    float* out = (float*)d_out;

    wt_kernel<<<dim3(64), dim3(256), 0, stream>>>(Wk, Wv, Wt);
    init_kernel<<<dim3(1), dim3(256), 0, stream>>>(noise_fg, noise_bg, mu_fg, ls_fg, mu_bg, ls_bg,
                                                   qbg_g, qbg_b, qbg_W, qfg_g, qfg_b, qfg_W,
                                                   slots_ws, q_ws);
    phaseA_kernel<<<dim3(NBLK_A), dim3(256), 0, stream>>>(x, ln_g, ln_b, Wt, q_ws, kb, vb, partials);
    update_kernel<<<dim3(1), dim3(256), 0, stream>>>(partials, NBLK_A, slots_ws, q_ws,
        gbg_k, gbg_rk, gbg_bias, gfg_k, gfg_rk, gfg_bias,
        mbg_g, mbg_b, mbg_W1, mbg_b1, mbg_W2, mbg_b2,
        mfg_g, mfg_b, mfg_W1, mfg_b1, mfg_W2, mfg_b2,
        qbg_g, qbg_b, qbg_W, qfg_g, qfg_b, qfg_W, 1, (float*)nullptr);
    iter2_kernel<<<dim3(NBLK_I2), dim3(256), 0, stream>>>(kb, vb, q_ws, out + 192, partials);
    update_kernel<<<dim3(1), dim3(256), 0, stream>>>(partials, NBLK_I2, slots_ws, q_ws,
        gbg_k, gbg_rk, gbg_bias, gfg_k, gfg_rk, gfg_bias,
        mbg_g, mbg_b, mbg_W1, mbg_b1, mbg_W2, mbg_b2,
        mfg_g, mfg_b, mfg_W1, mfg_b1, mfg_W2, mfg_b2,
        qbg_g, qbg_b, qbg_W, qfg_g, qfg_b, qfg_W, 0, out);
}

// Round 2
// 240.405 us; speedup vs baseline: 1.6489x; 1.6489x over previous
//
#include <hip/hip_runtime.h>
#include <hip/hip_bf16.h>

// SlotAttention fused implementation, round 2.
// LN folded into GEMM: LN(x)@W = rstd*(x@(g*W)) - (m*rstd)*c1 + c2.
// Pipeline: wt_init -> phaseA(stats + bf16 stage + MFMA + fixup + iter1 attn partials)
//           -> reduce -> update -> iter2 -> reduce -> update

#define N_TOK 262144
#define CIN 512
#define TILE_M 64
#define NBLK_A 512
#define NBLK_I2 1024
#define PSTRIDE 1024

typedef __attribute__((ext_vector_type(8))) short short8;
typedef __attribute__((ext_vector_type(4))) float f32x4;

__device__ __forceinline__ unsigned short f2bf(float f) {
    union { float f; unsigned u; } v; v.f = f;
    unsigned r = v.u + 0x7FFFu + ((v.u >> 16) & 1u);
    return (unsigned short)(r >> 16);
}
__device__ __forceinline__ unsigned pkbf(float a, float b) {
    return (unsigned)f2bf(a) | ((unsigned)f2bf(b) << 16);
}
__device__ __forceinline__ float bf2f(unsigned short u) {
    union { unsigned u; float f; } v; v.u = ((unsigned)u) << 16;
    return v.f;
}
__device__ __forceinline__ float sigmoidf_(float x) { return 1.f / (1.f + expf(-x)); }

__device__ __forceinline__ float q_from_slot(float v, const float* __restrict__ g,
                                             const float* __restrict__ b,
                                             const float* __restrict__ W, int lane) {
    float s = v, s2 = v * v;
#pragma unroll
    for (int d = 1; d < 64; d <<= 1) { s += __shfl_xor(s, d); s2 += __shfl_xor(s2, d); }
    float mean = s * (1.f / 64.f);
    float var = s2 * (1.f / 64.f) - mean * mean;
    float rstd = rsqrtf(var + 1e-3f);
    float hl = (v - mean) * rstd * g[lane] + b[lane];
    float acc = 0.f;
    for (int i = 0; i < 64; ++i) acc += __shfl(hl, i) * W[i * 64 + lane];
    return acc * 0.125f;
}

// ------- wt_init: blocks 0..127 build Wt (g*W bf16, transposed) + c1/c2; block 128 = slot init -------
__global__ __launch_bounds__(256) void wt_init_kernel(
    const float* __restrict__ Wk, const float* __restrict__ Wv,
    const float* __restrict__ ln_g, const float* __restrict__ ln_b,
    unsigned short* __restrict__ Wt, float* __restrict__ c12,
    const float* __restrict__ noise_fg, const float* __restrict__ noise_bg,
    const float* __restrict__ mu_fg, const float* __restrict__ ls_fg,
    const float* __restrict__ mu_bg, const float* __restrict__ ls_bg,
    const float* __restrict__ qbg_g, const float* __restrict__ qbg_b, const float* __restrict__ qbg_W,
    const float* __restrict__ qfg_g, const float* __restrict__ qfg_b, const float* __restrict__ qfg_W,
    float* __restrict__ slots_ws, float* __restrict__ q_ws) {
    int t = threadIdx.x;
    if (blockIdx.x < 128) {
        int j = blockIdx.x;
        const float* W = (j < 64) ? Wk : Wv;
        int jc = j & 63;
        float c1 = 0.f, c2 = 0.f;
        for (int i = t; i < 512; i += 256) {
            float wv = W[i * 64 + jc];
            float g = ln_g[i], b = ln_b[i];
            c1 += g * wv; c2 += b * wv;
            Wt[(size_t)j * 512 + i] = f2bf(g * wv);
        }
        __shared__ float s1[4], s2[4];
#pragma unroll
        for (int d = 1; d < 64; d <<= 1) { c1 += __shfl_xor(c1, d); c2 += __shfl_xor(c2, d); }
        if ((t & 63) == 0) { s1[t >> 6] = c1; s2[t >> 6] = c2; }
        __syncthreads();
        if (t == 0) {
            c12[j] = (s1[0] + s1[1]) + (s1[2] + s1[3]);
            c12[128 + j] = (s2[0] + s2[1]) + (s2[2] + s2[3]);
        }
    } else {
        if (t < 192) {
            int s = t >> 6, c = t & 63;
            float v = (s == 0) ? (mu_bg[c] + expf(ls_bg[c]) * noise_bg[c])
                               : (mu_fg[c] + expf(ls_fg[c]) * noise_fg[(s - 1) * 64 + c]);
            slots_ws[t] = v;
            const float* g = s ? qfg_g : qbg_g;
            const float* b = s ? qfg_b : qbg_b;
            const float* W = s ? qfg_W : qbg_W;
            q_ws[t] = q_from_slot(v, g, b, W, c);
        }
    }
}

// ------- phase A: stats + raw-x bf16 stage + MFMA + affine fixup + iter1 attn partials -------
__global__ __launch_bounds__(256, 2) void phaseA_kernel(
    const float* __restrict__ x, const unsigned short* __restrict__ Wt,
    const float* __restrict__ c12, const float* __restrict__ qv,
    unsigned short* __restrict__ kb, unsigned short* __restrict__ vb,
    float* __restrict__ partials) {
    __shared__ unsigned short SA[TILE_M * CIN];  // 64KB bf16 (swizzled); aliased as kvf f32 after MFMA
    __shared__ float q_s[192];
    __shared__ float w_s[64 * 4];
    __shared__ float2 rowstat[64];  // (rstd, mean*rstd)
    float* kvf = (float*)SA;        // [64][130]

    const int t = threadIdx.x;
    const int lane = t & 63;
    const int w = t >> 6;

    if (t < 192) q_s[t] = qv[t];

    // hoisted B fragments + per-column fixup constants
    short8 bfrag[16][2];
    float c1r[2], c2r[2];
#pragma unroll
    for (int nt = 0; nt < 2; ++nt) {
        int col = w * 32 + nt * 16 + (lane & 15);
        c1r[nt] = c12[col];
        c2r[nt] = c12[128 + col];
#pragma unroll
        for (int kk = 0; kk < 16; ++kk) {
            int off = kk * 32 + ((lane >> 4) << 3);
            bfrag[kk][nt] = *(const short8*)(Wt + (size_t)col * 512 + off);
        }
    }

    float upd_acc = 0.f;
    float sw_acc = 0.f;

    for (int tile = blockIdx.x; tile < N_TOK / TILE_M; tile += NBLK_A) {
        const size_t row0 = (size_t)tile * TILE_M;
        __syncthreads();  // protect SA/rowstat from previous iteration readers

        // ---- P1: 8 lanes per row -> sums + bf16 stage (no normalize) ----
#pragma unroll
        for (int p = 0; p < 2; ++p) {
            int r = w * 16 + p * 8 + (lane >> 3);
            int c8 = lane & 7;
            const float4* xr = (const float4*)(x + (row0 + r) * CIN) + c8 * 16;
            char* rowbase = (char*)SA + r * 1024;
            int bb = c8 * 128;
            int sw = (r & 7) << 4;
            float s = 0.f, s2 = 0.f;
#pragma unroll
            for (int i = 0; i < 8; ++i) {
                float4 a = xr[2 * i];
                float4 b = xr[2 * i + 1];
                s += (a.x + a.y) + (a.z + a.w) + (b.x + b.y) + (b.z + b.w);
                s2 = fmaf(a.x, a.x, s2); s2 = fmaf(a.y, a.y, s2);
                s2 = fmaf(a.z, a.z, s2); s2 = fmaf(a.w, a.w, s2);
                s2 = fmaf(b.x, b.x, s2); s2 = fmaf(b.y, b.y, s2);
                s2 = fmaf(b.z, b.z, s2); s2 = fmaf(b.w, b.w, s2);
                uint4 o;
                o.x = pkbf(a.x, a.y); o.y = pkbf(a.z, a.w);
                o.z = pkbf(b.x, b.y); o.w = pkbf(b.z, b.w);
                *(uint4*)(rowbase + ((bb + i * 16) ^ sw)) = o;
            }
#pragma unroll
            for (int d = 1; d < 8; d <<= 1) { s += __shfl_xor(s, d); s2 += __shfl_xor(s2, d); }
            if (c8 == 0) {
                float mean = s * (1.f / 512.f);
                float var = s2 * (1.f / 512.f) - mean * mean;
                float rstd = rsqrtf(var + 1e-3f);
                rowstat[r] = make_float2(rstd, mean * rstd);
            }
        }
        __syncthreads();

        // ---- P2: MFMA on raw-x bf16 ----
        f32x4 acc[4][2];
#pragma unroll
        for (int m = 0; m < 4; ++m) {
            acc[m][0] = (f32x4){0.f, 0.f, 0.f, 0.f};
            acc[m][1] = (f32x4){0.f, 0.f, 0.f, 0.f};
        }
#pragma unroll
        for (int kk = 0; kk < 16; ++kk) {
#pragma unroll
            for (int m = 0; m < 4; ++m) {
                int row = m * 16 + (lane & 15);
                int boff = (kk * 64 + ((lane >> 4) << 4)) ^ ((row & 7) << 4);
                short8 af = *(const short8*)((const char*)SA + row * 1024 + boff);
                acc[m][0] = __builtin_amdgcn_mfma_f32_16x16x32_bf16(af, bfrag[kk][0], acc[m][0], 0, 0, 0);
                acc[m][1] = __builtin_amdgcn_mfma_f32_16x16x32_bf16(af, bfrag[kk][1], acc[m][1], 0, 0, 0);
            }
        }
        __syncthreads();  // all SA reads done before aliasing as kvf

        // ---- P3: affine fixup + write kvf [64][130] ----
        float2 rs[16];
#pragma unroll
        for (int m = 0; m < 4; ++m)
#pragma unroll
            for (int j = 0; j < 4; ++j)
                rs[m * 4 + j] = rowstat[m * 16 + ((lane >> 4) << 2) + j];
#pragma unroll
        for (int m = 0; m < 4; ++m)
#pragma unroll
            for (int n = 0; n < 2; ++n)
#pragma unroll
                for (int j = 0; j < 4; ++j) {
                    int row = m * 16 + ((lane >> 4) << 2) + j;
                    int col = w * 32 + n * 16 + (lane & 15);
                    float val = fmaf(rs[m * 4 + j].x, acc[m][n][j],
                                     fmaf(-rs[m * 4 + j].y, c1r[n], c2r[n]));
                    kvf[row * 130 + col] = val;
                }
        __syncthreads();

        // ---- P4: bf16 store of k,v + wave0 softmax weights ----
        {
            int r = t >> 2, q4 = t & 3;
            unsigned short* dst = ((q4 < 2) ? kb : vb) + (row0 + r) * 64 + (q4 & 1) * 32;
            const float* src = &kvf[r * 130 + q4 * 32];
#pragma unroll
            for (int j = 0; j < 32; j += 8) {
                float2 p0 = *(const float2*)(src + j);
                float2 p1 = *(const float2*)(src + j + 2);
                float2 p2 = *(const float2*)(src + j + 4);
                float2 p3 = *(const float2*)(src + j + 6);
                uint4 o;
                o.x = pkbf(p0.x, p0.y);
                o.y = pkbf(p1.x, p1.y);
                o.z = pkbf(p2.x, p2.y);
                o.w = pkbf(p3.x, p3.y);
                *(uint4*)(dst + j) = o;
            }
        }
        if (t < 64) {
            int r = t;
            float l0 = 0.f, l1 = 0.f, l2 = 0.f;
#pragma unroll 8
            for (int c = 0; c < 64; c += 2) {
                float2 kv2 = *(const float2*)&kvf[r * 130 + c];
                l0 += kv2.x * q_s[c] + kv2.y * q_s[c + 1];
                l1 += kv2.x * q_s[64 + c] + kv2.y * q_s[64 + c + 1];
                l2 += kv2.x * q_s[128 + c] + kv2.y * q_s[128 + c + 1];
            }
            float mx = fmaxf(l0, fmaxf(l1, l2));
            float e0 = expf(l0 - mx), e1 = expf(l1 - mx), e2 = expf(l2 - mx);
            float inv = 1.f / (e0 + e1 + e2);
            w_s[r * 4 + 0] = e0 * inv + 1e-8f;
            w_s[r * 4 + 1] = e1 * inv + 1e-8f;
            w_s[r * 4 + 2] = e2 * inv + 1e-8f;
        }
        __syncthreads();

        // ---- P5: outer-product partial accumulate ----
        if (t < 192) {
            int s = t >> 6, c = t & 63;
            float a = 0.f;
            for (int r = 0; r < 64; ++r) a += w_s[r * 4 + s] * kvf[r * 130 + 64 + c];
            upd_acc += a;
        } else if (t < 195) {
            int s = t - 192;
            float a = 0.f;
            for (int r = 0; r < 64; ++r) a += w_s[r * 4 + s];
            sw_acc += a;
        }
    }
    if (t < 192) partials[(size_t)t * PSTRIDE + blockIdx.x] = upd_acc;
    else if (t < 195) partials[(size_t)t * PSTRIDE + blockIdx.x] = sw_acc;
}

// ------- iter 2: attention with q2, writes attn.T + partials (transposed) -------
__global__ __launch_bounds__(256) void iter2_kernel(
    const unsigned short* __restrict__ kb, const unsigned short* __restrict__ vb,
    const float* __restrict__ qv, float* __restrict__ attn_out, float* __restrict__ partials) {
    __shared__ float q_s[192];
    __shared__ float w_s[256 * 4];
    __shared__ unsigned short v_lds[256 * 64];
    int t = threadIdx.x;
    if (t < 192) q_s[t] = qv[t];
    __syncthreads();
    size_t r = (size_t)blockIdx.x * 256 + t;
    const unsigned short* krow = kb + r * 64;
    float l0 = 0.f, l1 = 0.f, l2 = 0.f;
#pragma unroll
    for (int i = 0; i < 8; ++i) {
        uint4 u = *(const uint4*)(krow + i * 8);
        unsigned uu[4] = {u.x, u.y, u.z, u.w};
#pragma unroll
        for (int p = 0; p < 4; ++p) {
            float fa = bf2f((unsigned short)(uu[p] & 0xffffu));
            float fb = bf2f((unsigned short)(uu[p] >> 16));
            int c = i * 8 + p * 2;
            l0 += fa * q_s[c] + fb * q_s[c + 1];
            l1 += fa * q_s[64 + c] + fb * q_s[64 + c + 1];
            l2 += fa * q_s[128 + c] + fb * q_s[128 + c + 1];
        }
    }
    float mx = fmaxf(l0, fmaxf(l1, l2));
    float e0 = expf(l0 - mx), e1 = expf(l1 - mx), e2 = expf(l2 - mx);
    float inv = 1.f / (e0 + e1 + e2);
    float a0 = e0 * inv, a1 = e1 * inv, a2 = e2 * inv;
    attn_out[r] = a0;
    attn_out[(size_t)N_TOK + r] = a1;
    attn_out[2 * (size_t)N_TOK + r] = a2;
    w_s[t * 4 + 0] = a0 + 1e-8f;
    w_s[t * 4 + 1] = a1 + 1e-8f;
    w_s[t * 4 + 2] = a2 + 1e-8f;
    {
        const uint4* vr = (const uint4*)(vb + r * 64);
        uint4* vl = (uint4*)(v_lds + t * 64);
#pragma unroll
        for (int i = 0; i < 8; ++i) vl[i] = vr[i];
    }
    __syncthreads();
    if (t < 192) {
        int s = t >> 6, c = t & 63;
        float part = 0.f;
        for (int r2 = 0; r2 < 256; ++r2) part += w_s[r2 * 4 + s] * bf2f(v_lds[r2 * 64 + c]);
        partials[(size_t)t * PSTRIDE + blockIdx.x] = part;
    } else if (t < 195) {
        int s = t - 192;
        float part = 0.f;
        for (int r2 = 0; r2 < 256; ++r2) part += w_s[r2 * 4 + s];
        partials[(size_t)t * PSTRIDE + blockIdx.x] = part;
    }
}

// ------- reduce: 195 blocks, one per column -------
__global__ __launch_bounds__(256) void reduce_kernel(const float* __restrict__ partials,
                                                     int nblk, float* __restrict__ reduced) {
    int col = blockIdx.x, t = threadIdx.x;
    float a = 0.f;
    for (int b = t; b < nblk; b += 256) a += partials[(size_t)col * PSTRIDE + b];
#pragma unroll
    for (int d = 1; d < 64; d <<= 1) a += __shfl_xor(a, d);
    __shared__ float ws_[4];
    if ((t & 63) == 0) ws_[t >> 6] = a;
    __syncthreads();
    if (t == 0) reduced[col] = (ws_[0] + ws_[1]) + (ws_[2] + ws_[3]);
}

// ------- update: GRU -> MLP -> (q | out slots) -------
__global__ __launch_bounds__(256) void update_kernel(
    const float* __restrict__ reduced,
    float* __restrict__ slots_ws, float* __restrict__ q_ws,
    const float* __restrict__ gbg_k, const float* __restrict__ gbg_rk, const float* __restrict__ gbg_bias,
    const float* __restrict__ gfg_k, const float* __restrict__ gfg_rk, const float* __restrict__ gfg_bias,
    const float* __restrict__ mbg_g, const float* __restrict__ mbg_b, const float* __restrict__ mbg_W1,
    const float* __restrict__ mbg_b1, const float* __restrict__ mbg_W2, const float* __restrict__ mbg_b2,
    const float* __restrict__ mfg_g, const float* __restrict__ mfg_b, const float* __restrict__ mfg_W1,
    const float* __restrict__ mfg_b1, const float* __restrict__ mfg_W2, const float* __restrict__ mfg_b2,
    const float* __restrict__ qbg_g, const float* __restrict__ qbg_b, const float* __restrict__ qbg_W,
    const float* __restrict__ qfg_g, const float* __restrict__ qfg_b, const float* __restrict__ qfg_W,
    int compute_q, float* __restrict__ out_slots) {
    __shared__ float upd[192], hslots[192], swv[3];
    __shared__ float xm[192], hm[192], gout[64], lnv[64], hid[64];
    int t = threadIdx.x;
    if (t < 192) { hslots[t] = slots_ws[t]; upd[t] = reduced[t]; }
    else if (t < 195) swv[t - 192] = reduced[t];
    __syncthreads();
    if (t < 192) upd[t] = upd[t] / swv[t >> 6];
    __syncthreads();

    for (int s = 0; s < 3; ++s) {
        const float* K = s ? gfg_k : gbg_k;
        const float* RK = s ? gfg_rk : gbg_rk;
        const float* BS = s ? gfg_bias : gbg_bias;
        if (t < 192) {
            float ax = BS[t], ah = BS[192 + t];
            const float* us = upd + s * 64;
            const float* hs = hslots + s * 64;
            for (int i = 0; i < 64; ++i) {
                ax += us[i] * K[i * 192 + t];
                ah += hs[i] * RK[i * 192 + t];
            }
            xm[t] = ax; hm[t] = ah;
        }
        __syncthreads();
        if (t < 64) {
            float z = sigmoidf_(xm[t] + hm[t]);
            float rg = sigmoidf_(xm[64 + t] + hm[64 + t]);
            float cand = tanhf(xm[128 + t] + rg * hm[128 + t]);
            gout[t] = z * hslots[s * 64 + t] + (1.f - z) * cand;
        }
        __syncthreads();
        const float* MG = s ? mfg_g : mbg_g;
        const float* MB = s ? mfg_b : mbg_b;
        const float* MW1 = s ? mfg_W1 : mbg_W1;
        const float* MB1 = s ? mfg_b1 : mbg_b1;
        const float* MW2 = s ? mfg_W2 : mbg_W2;
        const float* MB2 = s ? mfg_b2 : mbg_b2;
        if (t < 64) {
            float v = gout[t];
            float su = v, sq = v * v;
#pragma unroll
            for (int d = 1; d < 64; d <<= 1) { su += __shfl_xor(su, d); sq += __shfl_xor(sq, d); }
            float mean = su * (1.f / 64.f), var = sq * (1.f / 64.f) - mean * mean;
            float rstd = rsqrtf(var + 1e-3f);
            lnv[t] = (v - mean) * rstd * MG[t] + MB[t];
        }
        __syncthreads();
        if (t < 64) {
            float a = MB1[t];
            for (int i = 0; i < 64; ++i) a += lnv[i] * MW1[i * 64 + t];
            hid[t] = fmaxf(a, 0.f);
        }
        __syncthreads();
        if (t < 64) {
            float a = MB2[t];
            for (int i = 0; i < 64; ++i) a += hid[i] * MW2[i * 64 + t];
            hslots[s * 64 + t] = gout[t] + a;
        }
        __syncthreads();
    }
    if (t < 192) {
        slots_ws[t] = hslots[t];
        if (out_slots) out_slots[t] = hslots[t];
        if (compute_q) {
            int s = t >> 6, lane = t & 63;
            const float* g = s ? qfg_g : qbg_g;
            const float* b = s ? qfg_b : qbg_b;
            const float* W = s ? qfg_W : qbg_W;
            q_ws[t] = q_from_slot(hslots[t], g, b, W, lane);
        }
    }
}

extern "C" void kernel_launch(void* const* d_in, const int* in_sizes, int n_in,
                              void* d_out, int out_size, void* d_ws, size_t ws_size,
                              hipStream_t stream) {
    const float* x        = (const float*)d_in[0];
    const float* noise_fg = (const float*)d_in[1];
    const float* noise_bg = (const float*)d_in[2];
    const float* ln_g     = (const float*)d_in[3];
    const float* ln_b     = (const float*)d_in[4];
    const float* mu_fg    = (const float*)d_in[5];
    const float* ls_fg    = (const float*)d_in[6];
    const float* mu_bg    = (const float*)d_in[7];
    const float* ls_bg    = (const float*)d_in[8];
    const float* Wk       = (const float*)d_in[9];
    const float* Wv       = (const float*)d_in[10];
    const float* qfg_g    = (const float*)d_in[11];
    const float* qfg_b    = (const float*)d_in[12];
    const float* qfg_W    = (const float*)d_in[13];
    const float* qbg_g    = (const float*)d_in[14];
    const float* qbg_b    = (const float*)d_in[15];
    const float* qbg_W    = (const float*)d_in[16];
    const float* gfg_k    = (const float*)d_in[17];
    const float* gfg_rk   = (const float*)d_in[18];
    const float* gfg_bias = (const float*)d_in[19];
    const float* gbg_k    = (const float*)d_in[20];
    const float* gbg_rk   = (const float*)d_in[21];
    const float* gbg_bias = (const float*)d_in[22];
    const float* mfg_g    = (const float*)d_in[23];
    const float* mfg_b    = (const float*)d_in[24];
    const float* mfg_W1   = (const float*)d_in[25];
    const float* mfg_b1   = (const float*)d_in[26];
    const float* mfg_W2   = (const float*)d_in[27];
    const float* mfg_b2   = (const float*)d_in[28];
    const float* mbg_g    = (const float*)d_in[29];
    const float* mbg_b    = (const float*)d_in[30];
    const float* mbg_W1   = (const float*)d_in[31];
    const float* mbg_b1   = (const float*)d_in[32];
    const float* mbg_W2   = (const float*)d_in[33];
    const float* mbg_b2   = (const float*)d_in[34];

    char* ws = (char*)d_ws;
    unsigned short* Wt = (unsigned short*)ws;                  // 131072 B
    float* c12 = (float*)(ws + 131072);                        // 256 f32 = 1024 B
    unsigned short* kb = (unsigned short*)(ws + 132096);       // 32 MB
    unsigned short* vb = kb + (size_t)N_TOK * 64;              // 32 MB
    char* ws2 = ws + 132096 + (size_t)2 * N_TOK * 64 * 2;
    float* slots_ws = (float*)ws2;                             // 192
    float* q_ws = slots_ws + 192;                              // 192
    float* reduced = q_ws + 192;                               // 256 (padded)
    float* partials = reduced + 256;                           // 195 * PSTRIDE

    float* out = (float*)d_out;

    wt_init_kernel<<<dim3(129), dim3(256), 0, stream>>>(
        Wk, Wv, ln_g, ln_b, Wt, c12,
        noise_fg, noise_bg, mu_fg, ls_fg, mu_bg, ls_bg,
        qbg_g, qbg_b, qbg_W, qfg_g, qfg_b, qfg_W, slots_ws, q_ws);
    phaseA_kernel<<<dim3(NBLK_A), dim3(256), 0, stream>>>(x, Wt, c12, q_ws, kb, vb, partials);
    reduce_kernel<<<dim3(195), dim3(256), 0, stream>>>(partials, NBLK_A, reduced);
    update_kernel<<<dim3(1), dim3(256), 0, stream>>>(reduced, slots_ws, q_ws,
        gbg_k, gbg_rk, gbg_bias, gfg_k, gfg_rk, gfg_bias,
        mbg_g, mbg_b, mbg_W1, mbg_b1, mbg_W2, mbg_b2,
        mfg_g, mfg_b, mfg_W1, mfg_b1, mfg_W2, mfg_b2,
        qbg_g, qbg_b, qbg_W, qfg_g, qfg_b, qfg_W, 1, (float*)nullptr);
    iter2_kernel<<<dim3(NBLK_I2), dim3(256), 0, stream>>>(kb, vb, q_ws, out + 192, partials);
    reduce_kernel<<<dim3(195), dim3(256), 0, stream>>>(partials, NBLK_I2, reduced);
    update_kernel<<<dim3(1), dim3(256), 0, stream>>>(reduced, slots_ws, q_ws,
        gbg_k, gbg_rk, gbg_bias, gfg_k, gfg_rk, gfg_bias,
        mbg_g, mbg_b, mbg_W1, mbg_b1, mbg_W2, mbg_b2,
        mfg_g, mfg_b, mfg_W1, mfg_b1, mfg_W2, mfg_b2,
        qbg_g, qbg_b, qbg_W, qfg_g, qfg_b, qfg_W, 0, out);
}